// Round 2
// baseline (252.139 us; speedup 1.0000x reference)
//
#include <hip/hip_runtime.h>

#define BB 4
#define CC 256
#define NN 8192
#define HH 4

typedef unsigned short u16;
typedef __bf16 bf16x8 __attribute__((ext_vector_type(8)));
typedef float f32x4 __attribute__((ext_vector_type(4)));

__device__ __forceinline__ float bf2f(unsigned u) {
  return __uint_as_float(u << 16);
}
__device__ __forceinline__ u16 f2bf(float f) {
  unsigned u = __float_as_uint(f);
  return (u16)((u + 0x7fffu + ((u >> 16) & 1u)) >> 16);
}
__device__ __forceinline__ void bf8_to_f32(uint4 r, float* f) {
  f[0] = __uint_as_float(r.x << 16); f[1] = __uint_as_float(r.x & 0xffff0000u);
  f[2] = __uint_as_float(r.y << 16); f[3] = __uint_as_float(r.y & 0xffff0000u);
  f[4] = __uint_as_float(r.z << 16); f[5] = __uint_as_float(r.z & 0xffff0000u);
  f[6] = __uint_as_float(r.w << 16); f[7] = __uint_as_float(r.w & 0xffff0000u);
}
__device__ __forceinline__ void bf4_to_f32(uint2 r, float* f) {
  f[0] = __uint_as_float(r.x << 16); f[1] = __uint_as_float(r.x & 0xffff0000u);
  f[2] = __uint_as_float(r.y << 16); f[3] = __uint_as_float(r.y & 0xffff0000u);
}

// ---------------- weight f32 -> bf16 convert ----------------
__global__ __launch_bounds__(256) void cvt_kernel(const float* __restrict__ in,
                                                  u16* __restrict__ out, int n) {
  int i = blockIdx.x * 256 + threadIdx.x;
  if (i < n) out[i] = f2bf(in[i]);
}

// ---------------- x [B,C,N] f32 -> xt [B,N,C] bf16 ----------------
__global__ __launch_bounds__(256) void transpose_kernel(const float* __restrict__ x,
                                                        u16* __restrict__ xt) {
  __shared__ float T[64][65];
  const int b = blockIdx.z, c0 = blockIdx.y * 64, n0 = blockIdx.x * 64;
  const float* xp = x + ((size_t)b * CC + c0) * NN + n0;
#pragma unroll
  for (int it = 0; it < 4; ++it) {
    int idx = threadIdx.x + it * 256;
    int r = idx >> 4, seg = idx & 15;
    float4 v = *(const float4*)(xp + (size_t)r * NN + seg * 4);
    T[r][seg * 4 + 0] = v.x; T[r][seg * 4 + 1] = v.y;
    T[r][seg * 4 + 2] = v.z; T[r][seg * 4 + 3] = v.w;
  }
  __syncthreads();
  u16* op = xt + ((size_t)b * NN + n0) * CC + c0;
  const int j = threadIdx.x >> 2, g = threadIdx.x & 3;
#pragma unroll
  for (int i = 0; i < 4; ++i) {
    int c = g * 16 + i * 4;
    uint2 pk;
    pk.x = (unsigned)f2bf(T[c + 0][j]) | ((unsigned)f2bf(T[c + 1][j]) << 16);
    pk.y = (unsigned)f2bf(T[c + 2][j]) | ((unsigned)f2bf(T[c + 3][j]) << 16);
    *(uint2*)(op + (size_t)j * CC + c) = pk;
  }
}

// ---------------- generic 128x128 MFMA GEMM: out[m,o] = epi(sum_k A[m,k]*W[o,k]) ----------------
// MODE 0: Q proj  (elu(v+bias)+1)
// MODE 1: K proj  (elu(v+bias)+1)
// MODE 2: V proj  (v+bias)
// MODE 3: aug proj + BatchNorm fold (bias=ba, e0=bn_g, e1=bn_b, e2=bn_m, e3=bn_v)
// MODE 4: MLP1 relu, A split: k<256 from A1, k>=256 from A2 (both stride 256)
// MODE 5: MLP2 plain
template <int MODE>
__global__ __launch_bounds__(256) void gemm_kernel(
    const u16* __restrict__ A1, const u16* __restrict__ A2,
    const u16* __restrict__ W, const float* __restrict__ bias,
    const float* __restrict__ e0, const float* __restrict__ e1,
    const float* __restrict__ e2, const float* __restrict__ e3,
    u16* __restrict__ outp, int K, int O) {
  __shared__ u16 As[128][72];
  __shared__ u16 Ws[128][72];
  const int m0 = blockIdx.x * 128, o0 = blockIdx.y * 128;
  const int tid = threadIdx.x, lane = tid & 63, wave = tid >> 6;
  const int wm = (wave >> 1) * 64, wo = (wave & 1) * 64;
  const int fr = lane & 15, fq = lane >> 4;
  f32x4 acc[4][4] = {};
  const int nkt = K >> 6;
  for (int kt = 0; kt < nkt; ++kt) {
    const int k0 = kt << 6;
    const u16* Ap;
    int rsA;
    if (MODE == 4) {
      Ap = (k0 < 256) ? (A1 + k0) : (A2 + (k0 - 256));
      rsA = 256;
    } else {
      Ap = A1 + k0;
      rsA = K;
    }
    const u16* Wp = W + k0;
#pragma unroll
    for (int i = 0; i < 4; ++i) {
      int idx = tid + i * 256;
      int r = idx >> 3, s = idx & 7;
      *(uint4*)(&As[r][s * 8]) = *(const uint4*)(Ap + (size_t)(m0 + r) * rsA + s * 8);
      *(uint4*)(&Ws[r][s * 8]) = *(const uint4*)(Wp + (size_t)(o0 + r) * K + s * 8);
    }
    __syncthreads();
#pragma unroll
    for (int kk = 0; kk < 2; ++kk) {
      bf16x8 af[4], bfr[4];
#pragma unroll
      for (int mi = 0; mi < 4; ++mi)
        af[mi] = __builtin_bit_cast(bf16x8, *(const uint4*)(&As[wm + mi * 16 + fr][kk * 32 + fq * 8]));
#pragma unroll
      for (int oi = 0; oi < 4; ++oi)
        bfr[oi] = __builtin_bit_cast(bf16x8, *(const uint4*)(&Ws[wo + oi * 16 + fr][kk * 32 + fq * 8]));
#pragma unroll
      for (int mi = 0; mi < 4; ++mi)
#pragma unroll
        for (int oi = 0; oi < 4; ++oi)
          acc[mi][oi] = __builtin_amdgcn_mfma_f32_16x16x32_bf16(af[mi], bfr[oi], acc[mi][oi], 0, 0, 0);
    }
    __syncthreads();
  }
#pragma unroll
  for (int oi = 0; oi < 4; ++oi) {
    const int col = o0 + wo + oi * 16 + fr;
    float b0 = 0.f, sc = 1.f, sh = 0.f;
    if (MODE == 0 || MODE == 1 || MODE == 2) b0 = bias[col];
    if (MODE == 3) {
      sc = e0[col] * rsqrtf(e3[col] + 1e-5f);
      sh = (bias[col] - e2[col]) * sc + e1[col];
    }
#pragma unroll
    for (int mi = 0; mi < 4; ++mi) {
      const int rowb = m0 + wm + mi * 16 + fq * 4;
#pragma unroll
      for (int r = 0; r < 4; ++r) {
        float v = acc[mi][oi][r];
        if (MODE == 0 || MODE == 1) {
          v += b0;
          v = (v > 0.f) ? (v + 1.f) : __expf(v);
        } else if (MODE == 2) {
          v += b0;
        } else if (MODE == 3) {
          v = v * sc + sh;
        } else if (MODE == 4) {
          v = fmaxf(v, 0.f);
        }
        outp[(size_t)(rowb + r) * O + col] = f2bf(v);
      }
    }
  }
}

// ---------------- Ksum[b,c] = sum_n Kt[b,n,c] ----------------
__global__ __launch_bounds__(256) void ksum_kernel(const u16* __restrict__ Kt,
                                                   float* __restrict__ Ksum) {
  const int b = blockIdx.y, ch = blockIdx.x;
  const u16* p = Kt + ((size_t)b * NN + (size_t)ch * 128) * CC + threadIdx.x;
  float acc = 0.f;
  for (int i = 0; i < 128; ++i) acc += bf2f(p[(size_t)i * CC]);
  atomicAdd(&Ksum[b * CC + threadIdx.x], acc);
}

// ---------------- KV[b,h,dk,dv] += sum_n Kt[b,n,h*64+dk]*Vt[b,n,h*64+dv] ----------------
__global__ __launch_bounds__(256) void kv_kernel(const u16* __restrict__ Kt,
                                                 const u16* __restrict__ Vt,
                                                 float* __restrict__ KV) {
  __shared__ u16 Ks[128][72];
  __shared__ u16 Vs[128][72];
  const int b = blockIdx.z, h = blockIdx.y, ch = blockIdx.x, tid = threadIdx.x;
  const size_t base = ((size_t)b * NN + (size_t)ch * 128) * CC + h * 64;
#pragma unroll
  for (int i = 0; i < 4; ++i) {
    int idx = tid + i * 256;
    int r = idx >> 3, s = idx & 7;
    *(uint4*)(&Ks[r][s * 8]) = *(const uint4*)(Kt + base + (size_t)r * CC + s * 8);
    *(uint4*)(&Vs[r][s * 8]) = *(const uint4*)(Vt + base + (size_t)r * CC + s * 8);
  }
  __syncthreads();
  const int tdk = tid & 15, tdv = tid >> 4;
  float a[4][4] = {};
  for (int n = 0; n < 128; ++n) {
    float kq[4], vq[4];
    bf4_to_f32(*(const uint2*)(&Ks[n][tdk * 4]), kq);
    bf4_to_f32(*(const uint2*)(&Vs[n][tdv * 4]), vq);
#pragma unroll
    for (int i2 = 0; i2 < 4; ++i2)
#pragma unroll
      for (int j2 = 0; j2 < 4; ++j2) a[i2][j2] += kq[i2] * vq[j2];
  }
  float* o = KV + (((size_t)b * HH + h) << 12);
#pragma unroll
  for (int i2 = 0; i2 < 4; ++i2)
#pragma unroll
    for (int j2 = 0; j2 < 4; ++j2)
      atomicAdd(&o[(tdk * 4 + i2) * 64 + tdv * 4 + j2], a[i2][j2]);
}

// ---------------- KV f32 [bh,d,v] -> KVT bf16 [bh,v,d] ----------------
__global__ __launch_bounds__(256) void cvtkv_kernel(const float* __restrict__ KV,
                                                    u16* __restrict__ KVT) {
  int i = blockIdx.x * 256 + threadIdx.x;  // 65536 total
  int dd = i & 63, vv = (i >> 6) & 63, bh = i >> 12;
  KVT[i] = f2bf(KV[((size_t)bh * 64 + dd) * 64 + vv]);
}

// ---------------- Z[b,n,h] = 1/(where(Q.Ksum>thr)+eps) ----------------
__global__ __launch_bounds__(256) void score_kernel(const u16* __restrict__ Qt,
                                                    const float* __restrict__ Ksum,
                                                    const float* __restrict__ thrp,
                                                    float* __restrict__ Zbuf) {
  int gid = blockIdx.x * 256 + threadIdx.x;  // b*NN + n
  int b = gid >> 13;
  const u16* qp = Qt + (size_t)gid * CC;
  const float* ks = Ksum + b * CC;
  float acc[HH] = {0.f, 0.f, 0.f, 0.f};
  for (int c8 = 0; c8 < 32; ++c8) {
    uint4 raw = *(const uint4*)(qp + c8 * 8);
    float f[8];
    bf8_to_f32(raw, f);
    float s = 0.f;
#pragma unroll
    for (int j = 0; j < 8; ++j) s += f[j] * ks[c8 * 8 + j];
    acc[c8 >> 3] += s;
  }
  float thr = thrp[0];
  float4 z;
  z.x = 1.f / (((acc[0] > thr) ? acc[0] : 0.f) + 1e-6f);
  z.y = 1.f / (((acc[1] > thr) ? acc[1] : 0.f) + 1e-6f);
  z.z = 1.f / (((acc[2] > thr) ? acc[2] : 0.f) + 1e-6f);
  z.w = 1.f / (((acc[3] > thr) ? acc[3] : 0.f) + 1e-6f);
  *(float4*)(Zbuf + (size_t)gid * 4) = z;
}

// ---------------- msg[m, h*64+v] = Z[m,h] * sum_d Qt[m,h*64+d]*KVT[b,h,v,d] ----------------
__global__ __launch_bounds__(256) void msggemm_kernel(const u16* __restrict__ Qt,
                                                      const u16* __restrict__ KVT,
                                                      const float* __restrict__ Zbuf,
                                                      u16* __restrict__ msgln) {
  __shared__ u16 As[128][72];
  __shared__ u16 Ws[64][72];
  const int m0 = blockIdx.x * 128, h = blockIdx.y, b = blockIdx.z;
  const int tid = threadIdx.x, lane = tid & 63, wave = tid >> 6;
  const int wm = (wave >> 1) * 64, wo = (wave & 1) * 32;
  const int fr = lane & 15, fq = lane >> 4;
  const u16* Ap = Qt + ((size_t)b * NN + m0) * CC + h * 64;
#pragma unroll
  for (int i = 0; i < 4; ++i) {
    int idx = tid + i * 256;
    int r = idx >> 3, s = idx & 7;
    *(uint4*)(&As[r][s * 8]) = *(const uint4*)(Ap + (size_t)r * CC + s * 8);
  }
  const u16* Wp = KVT + (((size_t)b * HH + h) << 12);
#pragma unroll
  for (int i = 0; i < 2; ++i) {
    int idx = tid + i * 256;
    int r = idx >> 3, s = idx & 7;
    *(uint4*)(&Ws[r][s * 8]) = *(const uint4*)(Wp + (size_t)r * 64 + s * 8);
  }
  __syncthreads();
  f32x4 acc[4][2] = {};
#pragma unroll
  for (int kk = 0; kk < 2; ++kk) {
    bf16x8 af[4], bfr[2];
#pragma unroll
    for (int mi = 0; mi < 4; ++mi)
      af[mi] = __builtin_bit_cast(bf16x8, *(const uint4*)(&As[wm + mi * 16 + fr][kk * 32 + fq * 8]));
#pragma unroll
    for (int oi = 0; oi < 2; ++oi)
      bfr[oi] = __builtin_bit_cast(bf16x8, *(const uint4*)(&Ws[wo + oi * 16 + fr][kk * 32 + fq * 8]));
#pragma unroll
    for (int mi = 0; mi < 4; ++mi)
#pragma unroll
      for (int oi = 0; oi < 2; ++oi)
        acc[mi][oi] = __builtin_amdgcn_mfma_f32_16x16x32_bf16(af[mi], bfr[oi], acc[mi][oi], 0, 0, 0);
  }
#pragma unroll
  for (int oi = 0; oi < 2; ++oi) {
    const int col = h * 64 + wo + oi * 16 + fr;
#pragma unroll
    for (int mi = 0; mi < 4; ++mi) {
      const int rowb = m0 + wm + mi * 16 + fq * 4;
#pragma unroll
      for (int r = 0; r < 4; ++r) {
        const int row = rowb + r;
        float z = Zbuf[((size_t)b * NN + row) * HH + h];
        msgln[((size_t)b * NN + row) * CC + col] = f2bf(acc[mi][oi][r] * z);
      }
    }
  }
}

// ---------------- LayerNorm over C (one wave per row); AUG adds aug row ----------------
template <bool AUG>
__global__ __launch_bounds__(256) void ln_kernel(const u16* __restrict__ in,
                                                 u16* __restrict__ outb,
                                                 const float* __restrict__ g,
                                                 const float* __restrict__ bb,
                                                 const u16* __restrict__ aug) {
  const int tid = threadIdx.x, lane = tid & 63, w = tid >> 6;
  const size_t row0 = (size_t)blockIdx.x * 32;
  float gv[4], bv[4];
#pragma unroll
  for (int q = 0; q < 4; ++q) {
    gv[q] = g[lane + 64 * q];
    bv[q] = bb[lane + 64 * q];
  }
  for (int i = 0; i < 8; ++i) {
    const size_t row = row0 + i * 4 + w;
    const u16* p = in + row * CC;
    float v[4], s1 = 0.f, s2 = 0.f;
#pragma unroll
    for (int q = 0; q < 4; ++q) {
      v[q] = bf2f(p[lane + 64 * q]);
      s1 += v[q];
      s2 += v[q] * v[q];
    }
#pragma unroll
    for (int m = 1; m < 64; m <<= 1) {
      s1 += __shfl_xor(s1, m);
      s2 += __shfl_xor(s2, m);
    }
    const float mean = s1 * (1.f / CC);
    const float var = s2 * (1.f / CC) - mean * mean;
    const float rs = rsqrtf(var + 1e-5f);
    u16* o = outb + row * CC;
#pragma unroll
    for (int q = 0; q < 4; ++q) {
      float ov = (v[q] - mean) * rs * gv[q] + bv[q];
      if (AUG) ov += bf2f(aug[row * CC + lane + 64 * q]);
      o[lane + 64 * q] = f2bf(ov);
    }
  }
}

// ---------------- out[b,c,n] = tv[b,n,c] + x1[b,c,n]  (f32 out) ----------------
__global__ __launch_bounds__(256) void addout_kernel(const u16* __restrict__ tv,
                                                     const float* __restrict__ x1,
                                                     float* __restrict__ outp) {
  __shared__ float T[64][65];
  const int b = blockIdx.z, c0 = blockIdx.y * 64, n0 = blockIdx.x * 64;
  const u16* tp = tv + ((size_t)b * NN + n0) * CC + c0;
#pragma unroll
  for (int i = 0; i < 2; ++i) {
    int idx = threadIdx.x + i * 256;
    int r = idx >> 3, s = idx & 7;  // r = n-local, s = c-seg (8 bf16)
    uint4 raw = *(const uint4*)(tp + (size_t)r * CC + s * 8);
    float f[8];
    bf8_to_f32(raw, f);
#pragma unroll
    for (int j = 0; j < 8; ++j) T[s * 8 + j][r] = f[j];
  }
  __syncthreads();
  const float* xp = x1 + ((size_t)b * CC + c0) * NN + n0;
  float* op = outp + ((size_t)b * CC + c0) * NN + n0;
#pragma unroll
  for (int i = 0; i < 16; ++i) {
    int idx = threadIdx.x + i * 256;
    int c = idx >> 6, j = idx & 63;
    op[(size_t)c * NN + j] = T[c][j] + xp[(size_t)c * NN + j];
  }
}

extern "C" void kernel_launch(void* const* d_in, const int* in_sizes, int n_in,
                              void* d_out, int out_size, void* d_ws, size_t ws_size,
                              hipStream_t stream) {
  (void)in_sizes; (void)n_in; (void)out_size; (void)ws_size;
  const float* x1 = (const float*)d_in[0];
  const float* x2 = (const float*)d_in[1];
  const float* Wq = (const float*)d_in[2];
  const float* bq = (const float*)d_in[3];
  const float* Wk = (const float*)d_in[4];
  const float* bk = (const float*)d_in[5];
  const float* Wv = (const float*)d_in[6];
  const float* bv = (const float*)d_in[7];
  const float* thr = (const float*)d_in[8];
  const float* W1 = (const float*)d_in[9];
  const float* W2 = (const float*)d_in[10];
  const float* g1 = (const float*)d_in[11];
  const float* b1 = (const float*)d_in[12];
  const float* g2 = (const float*)d_in[13];
  const float* b2 = (const float*)d_in[14];
  const float* Wa = (const float*)d_in[15];
  const float* ba = (const float*)d_in[16];
  const float* bng = (const float*)d_in[17];
  const float* bnb = (const float*)d_in[18];
  const float* bnm = (const float*)d_in[19];
  const float* bnv = (const float*)d_in[20];
  float* out = (float*)d_out;

  char* ws = (char*)d_ws;
  constexpr size_t SZ = (size_t)BB * NN * CC * sizeof(u16);  // 16.78 MB
  u16* x1t = (u16*)(ws);
  u16* x2t = (u16*)(ws + SZ);
  u16* Qt = (u16*)(ws + 2 * SZ);
  u16* Kt = (u16*)(ws + 3 * SZ);
  u16* Vt = (u16*)(ws + 4 * SZ);
  u16* augt = (u16*)(ws + 5 * SZ);
  u16* msgln = (u16*)(ws + 6 * SZ);
  u16* h1 = Qt;    // reuse Qt+Kt (33.55 MB contiguous), free after msggemm
  u16* mlp2 = x2t; // reuse x2t, free after V projection
  u16* tv = Vt;    // reuse Vt for LN2 output, free after kv_kernel
  char* tail = ws + 7 * SZ;
  float* Ksum = (float*)tail;                        // 4 KB
  float* KVb = (float*)(tail + 4096);                // 256 KB
  float* Zbuf = (float*)(tail + 4096 + 262144);      // 512 KB
  u16* KVT = (u16*)(tail + 4096 + 262144 + 524288);  // 128 KB
  u16* Wqb = (u16*)(tail + 4096 + 262144 + 524288 + 131072);
  u16* Wkb = Wqb + CC * CC;
  u16* Wvb = Wkb + CC * CC;
  u16* Wab = Wvb + CC * CC;
  u16* W1b = Wab + CC * CC;
  u16* W2b = W1b + 512 * 512;
  // total ws use ~120 MiB

  // weight converts
  cvt_kernel<<<dim3(256), 256, 0, stream>>>(Wq, Wqb, CC * CC);
  cvt_kernel<<<dim3(256), 256, 0, stream>>>(Wk, Wkb, CC * CC);
  cvt_kernel<<<dim3(256), 256, 0, stream>>>(Wv, Wvb, CC * CC);
  cvt_kernel<<<dim3(256), 256, 0, stream>>>(Wa, Wab, CC * CC);
  cvt_kernel<<<dim3(1024), 256, 0, stream>>>(W1, W1b, 512 * 512);
  cvt_kernel<<<dim3(512), 256, 0, stream>>>(W2, W2b, 256 * 512);

  // transposes
  transpose_kernel<<<dim3(NN / 64, CC / 64, BB), 256, 0, stream>>>(x1, x1t);
  transpose_kernel<<<dim3(NN / 64, CC / 64, BB), 256, 0, stream>>>(x2, x2t);

  // projections (M = 32768 rows flattened across batch)
  gemm_kernel<0><<<dim3(256, 2), 256, 0, stream>>>(x1t, nullptr, Wqb, bq, nullptr, nullptr, nullptr, nullptr, Qt, 256, 256);
  gemm_kernel<1><<<dim3(256, 2), 256, 0, stream>>>(x2t, nullptr, Wkb, bk, nullptr, nullptr, nullptr, nullptr, Kt, 256, 256);
  gemm_kernel<2><<<dim3(256, 2), 256, 0, stream>>>(x2t, nullptr, Wvb, bv, nullptr, nullptr, nullptr, nullptr, Vt, 256, 256);
  gemm_kernel<3><<<dim3(256, 2), 256, 0, stream>>>(x1t, nullptr, Wab, ba, bng, bnb, bnm, bnv, augt, 256, 256);

  // attention core
  hipMemsetAsync(Ksum, 0, 4096, stream);
  hipMemsetAsync(KVb, 0, 262144, stream);
  ksum_kernel<<<dim3(64, BB), 256, 0, stream>>>(Kt, Ksum);
  kv_kernel<<<dim3(64, HH, BB), 256, 0, stream>>>(Kt, Vt, KVb);
  cvtkv_kernel<<<dim3(256), 256, 0, stream>>>(KVb, KVT);
  score_kernel<<<dim3(128), 256, 0, stream>>>(Qt, Ksum, thr, Zbuf);
  // NOTE: m0 is PER-BATCH here -> grid.x = NN/128 = 64 (256 was the round-1 OOB bug)
  msggemm_kernel<<<dim3(NN / 128, HH, BB), 256, 0, stream>>>(Qt, KVT, Zbuf, msgln);
  ln_kernel<false><<<dim3(1024), 256, 0, stream>>>(msgln, msgln, g1, b1, nullptr);

  // MLP
  gemm_kernel<4><<<dim3(256, 4), 256, 0, stream>>>(x1t, msgln, W1b, nullptr, nullptr, nullptr, nullptr, nullptr, h1, 512, 512);
  gemm_kernel<5><<<dim3(256, 2), 256, 0, stream>>>(h1, nullptr, W2b, nullptr, nullptr, nullptr, nullptr, nullptr, mlp2, 512, 256);

  // LN2 + aug, then transpose-add to output
  ln_kernel<true><<<dim3(1024), 256, 0, stream>>>(mlp2, tv, g2, b2, augt);
  addout_kernel<<<dim3(NN / 64, CC / 64, BB), 256, 0, stream>>>(tv, x1, out);
}

// Round 4
// 187.528 us; speedup vs baseline: 1.3445x; 1.3445x over previous
//
#include <hip/hip_runtime.h>

#define BB 4
#define CC 256
#define NN 8192
#define HH 4
#define NCH 16  // n-chunks for KV partial reduction

typedef unsigned short u16;
typedef __bf16 bf16x8 __attribute__((ext_vector_type(8)));
typedef float f32x4 __attribute__((ext_vector_type(4)));

__device__ __forceinline__ float bf2f(unsigned u) {
  return __uint_as_float(u << 16);
}
__device__ __forceinline__ u16 f2bf(float f) {
  unsigned u = __float_as_uint(f);
  return (u16)((u + 0x7fffu + ((u >> 16) & 1u)) >> 16);
}
__device__ __forceinline__ void bf8_to_f32(uint4 r, float* f) {
  f[0] = __uint_as_float(r.x << 16); f[1] = __uint_as_float(r.x & 0xffff0000u);
  f[2] = __uint_as_float(r.y << 16); f[3] = __uint_as_float(r.y & 0xffff0000u);
  f[4] = __uint_as_float(r.z << 16); f[5] = __uint_as_float(r.z & 0xffff0000u);
  f[6] = __uint_as_float(r.w << 16); f[7] = __uint_as_float(r.w & 0xffff0000u);
}

// ---------------- fused weight f32 -> bf16 convert (all 6 weights) ----------------
__global__ __launch_bounds__(256) void cvt_all_kernel(
    const float* __restrict__ wq, const float* __restrict__ wk,
    const float* __restrict__ wv, const float* __restrict__ wa,
    const float* __restrict__ w1, const float* __restrict__ w2,
    u16* __restrict__ oq, u16* __restrict__ ok, u16* __restrict__ ov,
    u16* __restrict__ oa, u16* __restrict__ o1, u16* __restrict__ o2) {
  int i = blockIdx.x * 256 + threadIdx.x;  // [0, 655360)
  const float* src;
  u16* dst;
  int off;
  if (i < 65536) { src = wq; dst = oq; off = i; }
  else if (i < 131072) { src = wk; dst = ok; off = i - 65536; }
  else if (i < 196608) { src = wv; dst = ov; off = i - 131072; }
  else if (i < 262144) { src = wa; dst = oa; off = i - 196608; }
  else if (i < 524288) { src = w1; dst = o1; off = i - 262144; }
  else { src = w2; dst = o2; off = i - 524288; }
  dst[off] = f2bf(src[off]);
}

// ---------------- x [B,C,N] f32 -> xt [B,N,C] bf16 (z<4: x1, z>=4: x2) ----------------
__global__ __launch_bounds__(256) void transpose_kernel(const float* __restrict__ x1,
                                                        const float* __restrict__ x2,
                                                        u16* __restrict__ x1t,
                                                        u16* __restrict__ x2t) {
  __shared__ float T[64][65];
  const int bz = blockIdx.z;
  const int b = bz & 3;
  const float* x = (bz < 4) ? x1 : x2;
  u16* xt = (bz < 4) ? x1t : x2t;
  const int c0 = blockIdx.y * 64, n0 = blockIdx.x * 64;
  const float* xp = x + ((size_t)b * CC + c0) * NN + n0;
#pragma unroll
  for (int it = 0; it < 4; ++it) {
    int idx = threadIdx.x + it * 256;
    int r = idx >> 4, seg = idx & 15;
    float4 v = *(const float4*)(xp + (size_t)r * NN + seg * 4);
    T[r][seg * 4 + 0] = v.x; T[r][seg * 4 + 1] = v.y;
    T[r][seg * 4 + 2] = v.z; T[r][seg * 4 + 3] = v.w;
  }
  __syncthreads();
  u16* op = xt + ((size_t)b * NN + n0) * CC + c0;
  const int j = threadIdx.x >> 2, g = threadIdx.x & 3;
#pragma unroll
  for (int i = 0; i < 4; ++i) {
    int c = g * 16 + i * 4;
    uint2 pk;
    pk.x = (unsigned)f2bf(T[c + 0][j]) | ((unsigned)f2bf(T[c + 1][j]) << 16);
    pk.y = (unsigned)f2bf(T[c + 2][j]) | ((unsigned)f2bf(T[c + 3][j]) << 16);
    *(uint2*)(op + (size_t)j * CC + c) = pk;
  }
}

// ---------------- generic 128x128 MFMA GEMM: out[m,o] = epi(sum_k A[m,k]*W[o,k]) ----------------
// MODE 0: Q proj  (elu+1), out [B*N, C]
// MODE 1: K proj  (elu+1), out TRANSPOSED [B, C, N]
// MODE 2: V proj  (+bias), out TRANSPOSED [B, C, N]
// MODE 3: aug proj + BatchNorm fold, out [B*N, C]
// MODE 4: MLP1 relu, A split: k<256 from A1, k>=256 from A2 (both stride 256)
// MODE 5: MLP2 plain
template <int MODE>
__global__ __launch_bounds__(256) void gemm_kernel(
    const u16* __restrict__ A1, const u16* __restrict__ A2,
    const u16* __restrict__ W, const float* __restrict__ bias,
    const float* __restrict__ e0, const float* __restrict__ e1,
    const float* __restrict__ e2, const float* __restrict__ e3,
    u16* __restrict__ outp, int K, int O) {
  __shared__ u16 As[128][72];
  __shared__ u16 Ws[128][72];
  const int m0 = blockIdx.x * 128, o0 = blockIdx.y * 128;
  const int tid = threadIdx.x, lane = tid & 63, wave = tid >> 6;
  const int wm = (wave >> 1) * 64, wo = (wave & 1) * 64;
  const int fr = lane & 15, fq = lane >> 4;
  f32x4 acc[4][4] = {};
  const int nkt = K >> 6;
  for (int kt = 0; kt < nkt; ++kt) {
    const int k0 = kt << 6;
    const u16* Ap;
    int rsA;
    if (MODE == 4) {
      Ap = (k0 < 256) ? (A1 + k0) : (A2 + (k0 - 256));
      rsA = 256;
    } else {
      Ap = A1 + k0;
      rsA = K;
    }
    const u16* Wp = W + k0;
#pragma unroll
    for (int i = 0; i < 4; ++i) {
      int idx = tid + i * 256;
      int r = idx >> 3, s = idx & 7;
      *(uint4*)(&As[r][s * 8]) = *(const uint4*)(Ap + (size_t)(m0 + r) * rsA + s * 8);
      *(uint4*)(&Ws[r][s * 8]) = *(const uint4*)(Wp + (size_t)(o0 + r) * K + s * 8);
    }
    __syncthreads();
#pragma unroll
    for (int kk = 0; kk < 2; ++kk) {
      bf16x8 af[4], bfr[4];
#pragma unroll
      for (int mi = 0; mi < 4; ++mi)
        af[mi] = __builtin_bit_cast(bf16x8, *(const uint4*)(&As[wm + mi * 16 + fr][kk * 32 + fq * 8]));
#pragma unroll
      for (int oi = 0; oi < 4; ++oi)
        bfr[oi] = __builtin_bit_cast(bf16x8, *(const uint4*)(&Ws[wo + oi * 16 + fr][kk * 32 + fq * 8]));
#pragma unroll
      for (int mi = 0; mi < 4; ++mi)
#pragma unroll
        for (int oi = 0; oi < 4; ++oi)
          acc[mi][oi] = __builtin_amdgcn_mfma_f32_16x16x32_bf16(af[mi], bfr[oi], acc[mi][oi], 0, 0, 0);
    }
    __syncthreads();
  }
  // epilogue
  const int bb_ = m0 >> 13;       // batch (tiles never straddle batch: 128 | 8192)
  const int nb = m0 & (NN - 1);   // n-offset within batch (for transposed modes)
#pragma unroll
  for (int oi = 0; oi < 4; ++oi) {
    const int col = o0 + wo + oi * 16 + fr;
    float b0 = 0.f, sc = 1.f, sh = 0.f;
    if (MODE == 0 || MODE == 1 || MODE == 2) b0 = bias[col];
    if (MODE == 3) {
      sc = e0[col] * rsqrtf(e3[col] + 1e-5f);
      sh = (bias[col] - e2[col]) * sc + e1[col];
    }
#pragma unroll
    for (int mi = 0; mi < 4; ++mi) {
      const int rowb = m0 + wm + mi * 16 + fq * 4;
      if (MODE == 1 || MODE == 2) {
        // transposed write: out[b, col, n], 4 consecutive n packed into one 8B store
        float v[4];
#pragma unroll
        for (int r = 0; r < 4; ++r) {
          float t = acc[mi][oi][r] + b0;
          if (MODE == 1) t = (t > 0.f) ? (t + 1.f) : __expf(t);
          v[r] = t;
        }
        uint2 pk;
        pk.x = (unsigned)f2bf(v[0]) | ((unsigned)f2bf(v[1]) << 16);
        pk.y = (unsigned)f2bf(v[2]) | ((unsigned)f2bf(v[3]) << 16);
        const int nloc = nb + wm + mi * 16 + fq * 4;
        *(uint2*)(outp + ((size_t)bb_ * CC + col) * NN + nloc) = pk;
      } else {
#pragma unroll
        for (int r = 0; r < 4; ++r) {
          float v = acc[mi][oi][r];
          if (MODE == 0) {
            v += b0;
            v = (v > 0.f) ? (v + 1.f) : __expf(v);
          } else if (MODE == 3) {
            v = v * sc + sh;
          } else if (MODE == 4) {
            v = fmaxf(v, 0.f);
          }
          outp[(size_t)(rowb + r) * O + col] = f2bf(v);
        }
      }
    }
  }
}

// ---------------- Ksum[b,c] = sum_n K2[b,c,n]  (coalesced, no atomics) ----------------
__global__ __launch_bounds__(256) void ksum_kernel(const u16* __restrict__ K2,
                                                   float* __restrict__ Ksum) {
  __shared__ float red[4];
  const int b = blockIdx.y, c = blockIdx.x, tid = threadIdx.x;
  const u16* p = K2 + ((size_t)b * CC + c) * NN;
  float acc = 0.f;
#pragma unroll
  for (int j = 0; j < 4; ++j) {
    uint4 raw = *(const uint4*)(p + (j * 256 + tid) * 8);
    float f[8];
    bf8_to_f32(raw, f);
#pragma unroll
    for (int q = 0; q < 8; ++q) acc += f[q];
  }
#pragma unroll
  for (int m = 1; m < 64; m <<= 1) acc += __shfl_xor(acc, m);
  if ((tid & 63) == 0) red[tid >> 6] = acc;
  __syncthreads();
  if (tid == 0) Ksum[b * CC + c] = red[0] + red[1] + red[2] + red[3];
}

// ---------------- KV partials via MFMA: Pkv[ch,bh,dk,dv] = sum_{n in chunk} K2[.,dk,n]*V2[.,dv,n] ----------------
__global__ __launch_bounds__(256) void kvpartial_kernel(const u16* __restrict__ K2,
                                                        const u16* __restrict__ V2,
                                                        float* __restrict__ Pkv) {
  __shared__ u16 Ks[64][72];
  __shared__ u16 Vs[64][72];
  const int b = blockIdx.z, h = blockIdx.y, ch = blockIdx.x;
  const int tid = threadIdx.x, lane = tid & 63, w = tid >> 6;
  const int fr = lane & 15, fq = lane >> 4;
  const size_t base = ((size_t)b * CC + h * 64) * NN + (size_t)ch * (NN / NCH);
  f32x4 acc[4] = {};
  for (int step = 0; step < (NN / NCH) / 64; ++step) {
#pragma unroll
    for (int i = 0; i < 2; ++i) {
      int r = (tid >> 3) + i * 32, s = tid & 7;
      *(uint4*)(&Ks[r][s * 8]) = *(const uint4*)(K2 + base + (size_t)r * NN + step * 64 + s * 8);
      *(uint4*)(&Vs[r][s * 8]) = *(const uint4*)(V2 + base + (size_t)r * NN + step * 64 + s * 8);
    }
    __syncthreads();
#pragma unroll
    for (int kk = 0; kk < 2; ++kk) {
      bf16x8 af = __builtin_bit_cast(bf16x8, *(const uint4*)(&Ks[w * 16 + fr][kk * 32 + fq * 8]));
#pragma unroll
      for (int oi = 0; oi < 4; ++oi) {
        bf16x8 bfr = __builtin_bit_cast(bf16x8, *(const uint4*)(&Vs[oi * 16 + fr][kk * 32 + fq * 8]));
        acc[oi] = __builtin_amdgcn_mfma_f32_16x16x32_bf16(af, bfr, acc[oi], 0, 0, 0);
      }
    }
    __syncthreads();
  }
  // D[dk][dv]: dk = w*16 + fq*4 + r, dv = oi*16 + fr
  float* o = Pkv + (((size_t)ch * (BB * HH) + b * HH + h) << 12);
#pragma unroll
  for (int oi = 0; oi < 4; ++oi)
#pragma unroll
    for (int r = 0; r < 4; ++r)
      o[(w * 16 + fq * 4 + r) * 64 + oi * 16 + fr] = acc[oi][r];
}

// ---------------- KVT[bh][dv][dk] = bf16( sum_ch Pkv[ch][bh][dk][dv] ) ----------------
__global__ __launch_bounds__(256) void kvreduce_kernel(const float* __restrict__ Pkv,
                                                       u16* __restrict__ KVT) {
  int i = blockIdx.x * 256 + threadIdx.x;  // [0, 65536) = [bh][dk][dv] for coalesced reads
  int bh = i >> 12, dk = (i >> 6) & 63, dv = i & 63;
  float s = 0.f;
#pragma unroll
  for (int ch = 0; ch < NCH; ++ch)
    s += Pkv[(((size_t)ch * (BB * HH) + bh) << 12) + (dk << 6) + dv];
  KVT[((size_t)bh << 12) + (dv << 6) + dk] = f2bf(s);
}

// ---------------- Z[b,n,h] = 1/(where(Q.Ksum>thr)+eps) ----------------
__global__ __launch_bounds__(256) void score_kernel(const u16* __restrict__ Qt,
                                                    const float* __restrict__ Ksum,
                                                    const float* __restrict__ thrp,
                                                    float* __restrict__ Zbuf) {
  int gid = blockIdx.x * 256 + threadIdx.x;  // b*NN + n
  int b = gid >> 13;
  const u16* qp = Qt + (size_t)gid * CC;
  const float* ks = Ksum + b * CC;
  float acc[HH] = {0.f, 0.f, 0.f, 0.f};
  for (int c8 = 0; c8 < 32; ++c8) {
    uint4 raw = *(const uint4*)(qp + c8 * 8);
    float f[8];
    bf8_to_f32(raw, f);
    float s = 0.f;
#pragma unroll
    for (int j = 0; j < 8; ++j) s += f[j] * ks[c8 * 8 + j];
    acc[c8 >> 3] += s;
  }
  float thr = thrp[0];
  float4 z;
  z.x = 1.f / (((acc[0] > thr) ? acc[0] : 0.f) + 1e-6f);
  z.y = 1.f / (((acc[1] > thr) ? acc[1] : 0.f) + 1e-6f);
  z.z = 1.f / (((acc[2] > thr) ? acc[2] : 0.f) + 1e-6f);
  z.w = 1.f / (((acc[3] > thr) ? acc[3] : 0.f) + 1e-6f);
  *(float4*)(Zbuf + (size_t)gid * 4) = z;
}

// ---------------- msg[m, h*64+v] = Z[m,h] * sum_d Qt[m,h*64+d]*KVT[b,h,v,d] ----------------
__global__ __launch_bounds__(256) void msggemm_kernel(const u16* __restrict__ Qt,
                                                      const u16* __restrict__ KVT,
                                                      const float* __restrict__ Zbuf,
                                                      u16* __restrict__ msgout) {
  __shared__ u16 As[128][72];
  __shared__ u16 Ws[64][72];
  const int m0 = blockIdx.x * 128, h = blockIdx.y, b = blockIdx.z;
  const int tid = threadIdx.x, lane = tid & 63, wave = tid >> 6;
  const int wm = (wave >> 1) * 64, wo = (wave & 1) * 32;
  const int fr = lane & 15, fq = lane >> 4;
  const u16* Ap = Qt + ((size_t)b * NN + m0) * CC + h * 64;
#pragma unroll
  for (int i = 0; i < 4; ++i) {
    int idx = tid + i * 256;
    int r = idx >> 3, s = idx & 7;
    *(uint4*)(&As[r][s * 8]) = *(const uint4*)(Ap + (size_t)r * CC + s * 8);
  }
  const u16* Wp = KVT + (((size_t)b * HH + h) << 12);
#pragma unroll
  for (int i = 0; i < 2; ++i) {
    int idx = tid + i * 256;
    int r = idx >> 3, s = idx & 7;
    *(uint4*)(&Ws[r][s * 8]) = *(const uint4*)(Wp + (size_t)r * 64 + s * 8);
  }
  __syncthreads();
  f32x4 acc[4][2] = {};
#pragma unroll
  for (int kk = 0; kk < 2; ++kk) {
    bf16x8 af[4], bfr[2];
#pragma unroll
    for (int mi = 0; mi < 4; ++mi)
      af[mi] = __builtin_bit_cast(bf16x8, *(const uint4*)(&As[wm + mi * 16 + fr][kk * 32 + fq * 8]));
#pragma unroll
    for (int oi = 0; oi < 2; ++oi)
      bfr[oi] = __builtin_bit_cast(bf16x8, *(const uint4*)(&Ws[wo + oi * 16 + fr][kk * 32 + fq * 8]));
#pragma unroll
    for (int mi = 0; mi < 4; ++mi)
#pragma unroll
      for (int oi = 0; oi < 2; ++oi)
        acc[mi][oi] = __builtin_amdgcn_mfma_f32_16x16x32_bf16(af[mi], bfr[oi], acc[mi][oi], 0, 0, 0);
  }
#pragma unroll
  for (int oi = 0; oi < 2; ++oi) {
    const int col = h * 64 + wo + oi * 16 + fr;
#pragma unroll
    for (int mi = 0; mi < 4; ++mi) {
      const int rowb = m0 + wm + mi * 16 + fq * 4;
#pragma unroll
      for (int r = 0; r < 4; ++r) {
        const int row = rowb + r;
        float z = Zbuf[((size_t)b * NN + row) * HH + h];
        msgout[((size_t)b * NN + row) * CC + col] = f2bf(acc[mi][oi][r] * z);
      }
    }
  }
}

// ---------------- LayerNorm over C (one wave per row); AUG adds aug row ----------------
// NOTE: must be called OUT-OF-PLACE (in != outb). In-place violated __restrict__ (R3 bug).
template <bool AUG>
__global__ __launch_bounds__(256) void ln_kernel(const u16* __restrict__ in,
                                                 u16* __restrict__ outb,
                                                 const float* __restrict__ g,
                                                 const float* __restrict__ bb,
                                                 const u16* __restrict__ aug) {
  const int tid = threadIdx.x, lane = tid & 63, w = tid >> 6;
  const size_t row0 = (size_t)blockIdx.x * 32;
  float gv[4], bv[4];
#pragma unroll
  for (int q = 0; q < 4; ++q) {
    gv[q] = g[lane + 64 * q];
    bv[q] = bb[lane + 64 * q];
  }
  for (int i = 0; i < 8; ++i) {
    const size_t row = row0 + i * 4 + w;
    const u16* p = in + row * CC;
    float v[4], s1 = 0.f, s2 = 0.f;
#pragma unroll
    for (int q = 0; q < 4; ++q) {
      v[q] = bf2f(p[lane + 64 * q]);
      s1 += v[q];
      s2 += v[q] * v[q];
    }
#pragma unroll
    for (int m = 1; m < 64; m <<= 1) {
      s1 += __shfl_xor(s1, m);
      s2 += __shfl_xor(s2, m);
    }
    const float mean = s1 * (1.f / CC);
    const float var = s2 * (1.f / CC) - mean * mean;
    const float rs = rsqrtf(var + 1e-5f);
    u16* o = outb + row * CC;
#pragma unroll
    for (int q = 0; q < 4; ++q) {
      float ov = (v[q] - mean) * rs * gv[q] + bv[q];
      if (AUG) ov += bf2f(aug[row * CC + lane + 64 * q]);
      o[lane + 64 * q] = f2bf(ov);
    }
  }
}

// ---------------- out[b,c,n] = tv[b,n,c] + x1[b,c,n]  (f32 out) ----------------
__global__ __launch_bounds__(256) void addout_kernel(const u16* __restrict__ tv,
                                                     const float* __restrict__ x1,
                                                     float* __restrict__ outp) {
  __shared__ float T[64][65];
  const int b = blockIdx.z, c0 = blockIdx.y * 64, n0 = blockIdx.x * 64;
  const u16* tp = tv + ((size_t)b * NN + n0) * CC + c0;
#pragma unroll
  for (int i = 0; i < 2; ++i) {
    int idx = threadIdx.x + i * 256;
    int r = idx >> 3, s = idx & 7;  // r = n-local, s = c-seg (8 bf16)
    uint4 raw = *(const uint4*)(tp + (size_t)r * CC + s * 8);
    float f[8];
    bf8_to_f32(raw, f);
#pragma unroll
    for (int j = 0; j < 8; ++j) T[s * 8 + j][r] = f[j];
  }
  __syncthreads();
  const float* xp = x1 + ((size_t)b * CC + c0) * NN + n0;
  float* op = outp + ((size_t)b * CC + c0) * NN + n0;
#pragma unroll
  for (int i = 0; i < 16; ++i) {
    int idx = threadIdx.x + i * 256;
    int c = idx >> 6, j = idx & 63;
    op[(size_t)c * NN + j] = T[c][j] + xp[(size_t)c * NN + j];
  }
}

extern "C" void kernel_launch(void* const* d_in, const int* in_sizes, int n_in,
                              void* d_out, int out_size, void* d_ws, size_t ws_size,
                              hipStream_t stream) {
  (void)in_sizes; (void)n_in; (void)out_size; (void)ws_size;
  const float* x1 = (const float*)d_in[0];
  const float* x2 = (const float*)d_in[1];
  const float* Wq = (const float*)d_in[2];
  const float* bq = (const float*)d_in[3];
  const float* Wk = (const float*)d_in[4];
  const float* bk = (const float*)d_in[5];
  const float* Wv = (const float*)d_in[6];
  const float* bv = (const float*)d_in[7];
  const float* thr = (const float*)d_in[8];
  const float* W1 = (const float*)d_in[9];
  const float* W2 = (const float*)d_in[10];
  const float* g1 = (const float*)d_in[11];
  const float* b1 = (const float*)d_in[12];
  const float* g2 = (const float*)d_in[13];
  const float* b2 = (const float*)d_in[14];
  const float* Wa = (const float*)d_in[15];
  const float* ba = (const float*)d_in[16];
  const float* bng = (const float*)d_in[17];
  const float* bnb = (const float*)d_in[18];
  const float* bnm = (const float*)d_in[19];
  const float* bnv = (const float*)d_in[20];
  float* out = (float*)d_out;

  // Slot lifetime map (each slot SZ = 16.78 MB; all uses strictly stream-ordered):
  //  slot 0: x1t                    (live entire call)
  //  slot 1: x2t -> mlp2
  //  slot 2: Qt  -> h1(lo half)
  //  slot 3: K2  -> h1(hi half)
  //  slot 4: V2  -> msgN -> tv      (V2 dead after kvpartial; msgN: ln1 w -> gemm4 r; tv: ln2 w -> addout r)
  //  slot 5: augt                   (live until ln2)
  //  slot 6: Pkv (first 4MB) -> msgout (msggemm w -> ln1 r)
  char* ws = (char*)d_ws;
  constexpr size_t SZ = (size_t)BB * NN * CC * sizeof(u16);  // 16.78 MB
  u16* x1t = (u16*)(ws);
  u16* x2t = (u16*)(ws + SZ);
  u16* Qt = (u16*)(ws + 2 * SZ);
  u16* K2 = (u16*)(ws + 3 * SZ);  // [B,C,N] layout
  u16* V2 = (u16*)(ws + 4 * SZ);  // [B,C,N] layout
  u16* augt = (u16*)(ws + 5 * SZ);
  u16* msgout = (u16*)(ws + 6 * SZ);
  u16* h1 = Qt;      // slots 2+3 (33.55 MB contiguous)
  u16* mlp2 = x2t;   // slot 1, after x2t dead
  u16* msgN = V2;    // slot 4, after V2 dead (LN1 output -- OUT-OF-PLACE, no aliased call)
  u16* tv = V2;      // slot 4, after msgN consumed by gemm<4>
  float* Pkv = (float*)msgout;  // 4 MB partials; consumed by kvreduce before msggemm writes
  char* tail = ws + 7 * SZ;
  float* Ksum = (float*)tail;                   // 4 KB
  float* Zbuf = (float*)(tail + 4096);          // 512 KB
  u16* KVT = (u16*)(tail + 4096 + 524288);      // 128 KB
  u16* Wqb = (u16*)(tail + 4096 + 524288 + 131072);
  u16* Wkb = Wqb + CC * CC;
  u16* Wvb = Wkb + CC * CC;
  u16* Wab = Wvb + CC * CC;
  u16* W1b = Wab + CC * CC;
  u16* W2b = W1b + 512 * 512;
  // total ws use ~119.4 MiB

  // fused weight converts (one launch)
  cvt_all_kernel<<<dim3(2560), 256, 0, stream>>>(Wq, Wk, Wv, Wa, W1, W2,
                                                 Wqb, Wkb, Wvb, Wab, W1b, W2b);

  // fused transposes (x1 and x2 in one launch)
  transpose_kernel<<<dim3(NN / 64, CC / 64, 2 * BB), 256, 0, stream>>>(x1, x2, x1t, x2t);

  // projections (M = 32768 rows flattened across batch)
  gemm_kernel<0><<<dim3(256, 2), 256, 0, stream>>>(x1t, nullptr, Wqb, bq, nullptr, nullptr, nullptr, nullptr, Qt, 256, 256);
  gemm_kernel<1><<<dim3(256, 2), 256, 0, stream>>>(x2t, nullptr, Wkb, bk, nullptr, nullptr, nullptr, nullptr, K2, 256, 256);
  gemm_kernel<2><<<dim3(256, 2), 256, 0, stream>>>(x2t, nullptr, Wvb, bv, nullptr, nullptr, nullptr, nullptr, V2, 256, 256);
  gemm_kernel<3><<<dim3(256, 2), 256, 0, stream>>>(x1t, nullptr, Wab, ba, bng, bnb, bnm, bnv, augt, 256, 256);

  // attention core (no atomics anywhere)
  ksum_kernel<<<dim3(CC, BB), 256, 0, stream>>>(K2, Ksum);
  kvpartial_kernel<<<dim3(NCH, HH, BB), 256, 0, stream>>>(K2, V2, Pkv);
  kvreduce_kernel<<<dim3(256), 256, 0, stream>>>(Pkv, KVT);
  score_kernel<<<dim3(128), 256, 0, stream>>>(Qt, Ksum, thr, Zbuf);
  // m0 is PER-BATCH here -> grid.x = NN/128
  msggemm_kernel<<<dim3(NN / 128, HH, BB), 256, 0, stream>>>(Qt, KVT, Zbuf, msgout);
  // LN1: OUT-OF-PLACE (msgout -> msgN). In-place in==out with __restrict__ was R3's UB.
  ln_kernel<false><<<dim3(1024), 256, 0, stream>>>(msgout, msgN, g1, b1, nullptr);

  // MLP
  gemm_kernel<4><<<dim3(256, 4), 256, 0, stream>>>(x1t, msgN, W1b, nullptr, nullptr, nullptr, nullptr, nullptr, h1, 512, 512);
  gemm_kernel<5><<<dim3(256, 2), 256, 0, stream>>>(h1, nullptr, W2b, nullptr, nullptr, nullptr, nullptr, nullptr, mlp2, 512, 256);

  // LN2 + aug, then transpose-add to output
  ln_kernel<true><<<dim3(1024), 256, 0, stream>>>(mlp2, tv, g2, b2, augt);
  addout_kernel<<<dim3(NN / 64, CC / 64, BB), 256, 0, stream>>>(tv, x1, out);
}